// Round 18
// baseline (196.827 us; speedup 1.0000x reference)
//
#include <hip/hip_runtime.h>

#define NTOK 4096
#define CHAN 512
#define GSIZE 65536
#define RSQRT2 0.7071067811865476f
#define SCALE 0.17677669529663687f   // 1/sqrt(32)
#define WB_OFF 32768
#define QT_OFF (WB_OFF + 2097152)
#define WS_NEEDED ((size_t)(QT_OFF + 4194304))

typedef unsigned short ushort_t;
typedef __attribute__((ext_vector_type(8))) short bf16x8;
typedef __attribute__((ext_vector_type(8))) _Float16 f16x8;
typedef __attribute__((ext_vector_type(4))) float f32x4;

__device__ __forceinline__ ushort_t f2b(float f) {
    unsigned u = __float_as_uint(f);
    unsigned r = (u + 0x7FFFu + ((u >> 16) & 1u)) >> 16;
    return (ushort_t)r;
}
__device__ __forceinline__ unsigned pack2r(float a, float b) {
    unsigned ua = __float_as_uint(a), ub = __float_as_uint(b);
    return ((ua + 0x8000u) >> 16) | ((ub + 0x8000u) & 0xFFFF0000u);
}
__device__ __forceinline__ unsigned packh2(float a, float b) {
    return __builtin_bit_cast(unsigned, __builtin_amdgcn_cvt_pkrtz(a, b));
}
__device__ __forceinline__ ushort_t f2h(float f) {
    return (ushort_t)(packh2(f, f) & 0xFFFFu);
}
__device__ __forceinline__ bf16x8 ldfrag(const ushort_t* p) {
    return __builtin_bit_cast(bf16x8, *(const uint4*)p);
}
__device__ __forceinline__ f16x8 ldfragh(const ushort_t* p) {
    return __builtin_bit_cast(f16x8, *(const uint4*)p);
}

__global__ void diag_kernel(float* out, float v) {
    if (threadIdx.x == 0 && blockIdx.x == 0) out[0] = v;
}

// ---- GN pass A: per-channel sums. One block per channel (512 blocks).
__global__ __launch_bounds__(256) void gn_sums(const float* __restrict__ x,
                                               float* __restrict__ S,
                                               float* __restrict__ SS) {
    int c = blockIdx.x, t = threadIdx.x;
    const float4* p = (const float4*)(x + (size_t)c * 4096);
    float s = 0.f, ss = 0.f;
    #pragma unroll
    for (int i = 0; i < 4; i++) {
        float4 f = p[i * 256 + t];
        s += f.x + f.y + f.z + f.w;
        ss += f.x * f.x + f.y * f.y + f.z * f.z + f.w * f.w;
    }
    #pragma unroll
    for (int off = 32; off > 0; off >>= 1) {
        s += __shfl_xor(s, off);
        ss += __shfl_xor(ss, off);
    }
    __shared__ float as[4], bs[4];
    int w = t >> 6;
    if ((t & 63) == 0) { as[w] = s; bs[w] = ss; }
    __syncthreads();
    if (t == 0) {
        S[c] = as[0] + as[1] + as[2] + as[3];
        SS[c] = bs[0] + bs[1] + bs[2] + bs[3];
    }
}

// ---- GN pass B: coefficients. 1 block x 512 threads (thread = channel).
__global__ __launch_bounds__(512) void gn_coef(const float* __restrict__ S,
                                               const float* __restrict__ SS,
                                               const float* __restrict__ gnw,
                                               const float* __restrict__ gnb,
                                               float* __restrict__ qa,
                                               float* __restrict__ qd,
                                               float* __restrict__ va,
                                               float* __restrict__ vd) {
    int c = threadIdx.x;
    float Sc = S[c], SSc = SS[c];
    float gs = Sc, gss = SSc;
    #pragma unroll
    for (int off = 1; off < 16; off <<= 1) {
        gs += __shfl_xor(gs, off);
        gss += __shfl_xor(gss, off);
    }
    float mu = gs * (1.f / GSIZE);
    float var = gss * (1.f / GSIZE) - mu * mu;
    float r1 = rsqrtf(var + 1e-6f);
    float wc = gnw[c], bc = gnb[c];
    float a1 = r1 * wc;
    float d1 = bc - mu * a1;
    qa[c] = a1; qd[c] = d1;
    float S2 = a1 * Sc + 4096.f * d1;
    float SS2 = a1 * a1 * SSc + 2.f * a1 * d1 * Sc + 4096.f * d1 * d1;
    float gs2 = S2, gss2 = SS2;
    #pragma unroll
    for (int off = 1; off < 16; off <<= 1) {
        gs2 += __shfl_xor(gs2, off);
        gss2 += __shfl_xor(gss2, off);
    }
    float mu2 = gs2 * (1.f / GSIZE);
    float var2 = gss2 * (1.f / GSIZE) - mu2 * mu2;
    float r2 = rsqrtf(var2 + 1e-6f);
    float a2 = r2 * wc;
    va[c] = a1 * a2;
    vd[c] = a2 * (d1 - mu2) + bc;
}

// ---- Fold GN offsets into biases: b'[o] = b[o] + sum_c W[o][c]*d[c].
__global__ __launch_bounds__(256) void bias_fold(const float* __restrict__ wq,
                                                 const float* __restrict__ wk,
                                                 const float* __restrict__ wv,
                                                 const float* __restrict__ bq,
                                                 const float* __restrict__ bk,
                                                 const float* __restrict__ bv,
                                                 const float* __restrict__ qd,
                                                 const float* __restrict__ vd,
                                                 float* __restrict__ bqf,
                                                 float* __restrict__ bkf,
                                                 float* __restrict__ bvf) {
    int row = blockIdx.x * 4 + (threadIdx.x >> 6);   // 0..1535
    int lane = threadIdx.x & 63;
    int m = row >> 9;
    int o = row & 511;
    const float* W = (m == 0) ? wq : (m == 1) ? wk : wv;
    const float* b = (m == 0) ? bq : (m == 1) ? bk : bv;
    const float* d = (m == 0) ? qd : vd;
    float* outp    = (m == 0) ? bqf : (m == 1) ? bkf : bvf;
    const float4* wr = (const float4*)(W + (size_t)o * 512) + lane * 2;
    const float4* dr = (const float4*)d + lane * 2;
    float4 a0 = wr[0], a1 = wr[1], d0 = dr[0], d1 = dr[1];
    float acc = a0.x * d0.x + a0.y * d0.y + a0.z * d0.z + a0.w * d0.w
              + a1.x * d1.x + a1.y * d1.y + a1.z * d1.z + a1.w * d1.w;
    #pragma unroll
    for (int off = 32; off > 0; off >>= 1) acc += __shfl_xor(acc, off);
    if (lane == 0) outp[o] = b[o] + acc;
}

// ---- Weight prep: fp32 -> bf16 once, GN affine folded into wq/wk/wv.
__global__ __launch_bounds__(256) void wprep(const float* __restrict__ wq,
                                             const float* __restrict__ wk,
                                             const float* __restrict__ wv,
                                             const float* __restrict__ wo,
                                             const float* __restrict__ qa,
                                             const float* __restrict__ va,
                                             ushort_t* __restrict__ Wb) {
    int y = blockIdx.y;
    const float* src = (y == 0) ? wq : (y == 1) ? wk : (y == 2) ? wv : wo;
    int i = (blockIdx.x * 256 + threadIdx.x) * 4;
    float4 f = *(const float4*)(src + i);
    if (y < 3) {
        const float* aff = (y == 0) ? qa : va;
        float4 a = *(const float4*)(aff + (i & 511));
        f.x *= a.x; f.y *= a.y; f.z *= a.z; f.w *= a.w;
    }
    uint2 u;
    u.x = pack2r(f.x, f.y);
    u.y = pack2r(f.z, f.w);
    *(uint2*)(Wb + (size_t)y * 262144 + i) = u;
}

// ---- QKV projection. Tile 128m x 64n, K-step 32, grid (64, 12).
// A = Wb uint4 copy; B = x fp32 read directly (chan-pair pack, no affine).
__global__ __launch_bounds__(256) void qkv_mfma(const float* __restrict__ x,
                                                const ushort_t* __restrict__ Wb,
                                                const float* __restrict__ bqf,
                                                const float* __restrict__ bkf,
                                                const float* __restrict__ bvf,
                                                ushort_t* __restrict__ QT,
                                                ushort_t* __restrict__ KT,
                                                ushort_t* __restrict__ Vb) {
    __shared__ __align__(16) ushort_t Wl[128][40];
    __shared__ __align__(16) ushort_t Bn[64][40];
    __shared__ __align__(16) ushort_t Tl[64][136];
    int t = threadIdx.x;
    int nbase = blockIdx.x << 6;
    int y = blockIdx.y;
    int buf = y >> 2;
    int obase = (y & 3) << 7;
    const ushort_t* Wsrc = Wb + (size_t)buf * 262144;
    const float* bias = (buf == 0) ? bqf : (buf == 1) ? bkf : bvf;

    int w = t >> 6, lane = t & 63, q15 = lane & 15, quad = lane >> 4;
    f32x4 acc[2][4];
    #pragma unroll
    for (int i = 0; i < 2; i++)
        #pragma unroll
        for (int j = 0; j < 4; j++) acc[i][j] = (f32x4){0.f, 0.f, 0.f, 0.f};

    int cpair = t >> 4, ngroup = t & 15;
    for (int ck = 0; ck < 512; ck += 32) {
        __syncthreads();
        #pragma unroll
        for (int i = 0; i < 2; i++) {      // A: 512 uint4 = 128 rows x 32 k
            int idx = 2 * t + i;
            int row = idx >> 2, seg = idx & 3;
            *(uint4*)&Wl[row][seg * 8] =
                *(const uint4*)&Wsrc[(size_t)(obase + row) * 512 + ck + seg * 8];
        }
        {   // B: 64 tok x 32 chans from x, chan-pair packed
            int c0 = ck + 2 * cpair;
            int n0 = nbase + ngroup * 4;
            float4 fa = *(const float4*)&x[(size_t)c0 * NTOK + n0];
            float4 fb = *(const float4*)&x[(size_t)(c0 + 1) * NTOK + n0];
            unsigned* brow;
            brow = (unsigned*)&Bn[ngroup * 4 + 0][0]; brow[cpair] = pack2r(fa.x, fb.x);
            brow = (unsigned*)&Bn[ngroup * 4 + 1][0]; brow[cpair] = pack2r(fa.y, fb.y);
            brow = (unsigned*)&Bn[ngroup * 4 + 2][0]; brow[cpair] = pack2r(fa.z, fb.z);
            brow = (unsigned*)&Bn[ngroup * 4 + 3][0]; brow[cpair] = pack2r(fa.w, fb.w);
        }
        __syncthreads();
        bf16x8 af0 = ldfrag(&Wl[w * 32 + q15][quad * 8]);
        bf16x8 af1 = ldfrag(&Wl[w * 32 + 16 + q15][quad * 8]);
        #pragma unroll
        for (int n8 = 0; n8 < 4; n8++) {
            bf16x8 bfv = ldfrag(&Bn[n8 * 16 + q15][quad * 8]);
            acc[0][n8] = __builtin_amdgcn_mfma_f32_16x16x32_bf16(af0, bfv, acc[0][n8], 0, 0, 0);
            acc[1][n8] = __builtin_amdgcn_mfma_f32_16x16x32_bf16(af1, bfv, acc[1][n8], 0, 0, 0);
        }
    }

    if (buf == 2) {   // V: f16 [chan][tok]
        #pragma unroll
        for (int mi = 0; mi < 2; mi++)
            #pragma unroll
            for (int r = 0; r < 4; r++) {
                int o = obase + w * 32 + mi * 16 + quad * 4 + r;
                float bo = bias[o];
                #pragma unroll
                for (int n8 = 0; n8 < 4; n8++)
                    Vb[(size_t)o * NTOK + nbase + n8 * 16 + q15] = f2h(acc[mi][n8][r] + bo);
            }
        return;
    }

    // Q/K: transpose via Tl, full 1024-uint4 flush
    ushort_t* dstT = (buf == 0) ? QT : KT;
    float qs = (buf == 0) ? SCALE : 1.0f;
    __syncthreads();
    #pragma unroll
    for (int mi = 0; mi < 2; mi++)
        #pragma unroll
        for (int r = 0; r < 4; r++) {
            int mloc = w * 32 + mi * 16 + quad * 4 + r;
            float bo = bias[obase + mloc];
            #pragma unroll
            for (int n8 = 0; n8 < 4; n8++)
                Tl[n8 * 16 + q15][mloc] = f2b((acc[mi][n8][r] + bo) * qs);
        }
    __syncthreads();
    #pragma unroll
    for (int i = 0; i < 4; i++) {
        int idx = 4 * t + i;                // 1024 uint4: 64 rows x 16 segs
        int row = idx >> 4, ch = idx & 15;
        uint4 u = *(const uint4*)&Tl[row][ch * 8];
        *(uint4*)&dstT[(size_t)(nbase + row) * 512 + obase + ch * 8] = u;
    }
}

// ---- Attention v7: 128 q/block, 4 waves x 32 q (2 Q-frags per wave —
// halves kf/Vt LDS reads per query vs v6). K-tile 128, two 64-key sub-passes,
// QK bf16, __expf, P/V f16, l via ones-MFMA. O overwrites QT rows in place.
__global__ __launch_bounds__(256) void attn_v7(ushort_t* __restrict__ QT,
                                               const ushort_t* __restrict__ KT,
                                               const ushort_t* __restrict__ V) {
    __shared__ __align__(16) ushort_t Kt[128][40];    // [key][32 chans] bf16
    __shared__ __align__(16) ushort_t Vt[32][136];    // [d][128 keys] f16
    __shared__ __align__(16) unsigned Plu[4][32][36]; // per-wave [q][key-pairs] f16
    int h = blockIdx.y;
    int t = threadIdx.x;
    int w = t >> 6, lane = t & 63, q15 = lane & 15, quad = lane >> 4;
    int qbase = (blockIdx.x << 7) + w * 32;           // wave-private 32 queries
    int hc = h * 32;
    const ushort_t* Vh = V + (size_t)hc * NTOK;

    bf16x8 qf[2];
    #pragma unroll
    for (int qi = 0; qi < 2; qi++)
        qf[qi] = ldfrag(&QT[(size_t)(qbase + qi * 16 + q15) * 512 + hc + quad * 8]);

    const uint4 onesu = {0x3C003C00u, 0x3C003C00u, 0x3C003C00u, 0x3C003C00u};
    const f16x8 ones = __builtin_bit_cast(f16x8, onesu);

    f32x4 o[2][2];
    #pragma unroll
    for (int qi = 0; qi < 2; qi++)
        #pragma unroll
        for (int dc = 0; dc < 2; dc++) o[qi][dc] = (f32x4){0.f, 0.f, 0.f, 0.f};
    f32x4 lacc[2] = {{0.f, 0.f, 0.f, 0.f}, {0.f, 0.f, 0.f, 0.f}};

    for (int j0 = 0; j0 < NTOK; j0 += 128) {
        __syncthreads();
        #pragma unroll
        for (int i = 0; i < 2; i++) {      // K: 512 uint4 (128 rows x 4 segs)
            int idx = t + (i << 8);
            int krow = idx >> 2, kseg = idx & 3;
            *(uint4*)&Kt[krow][kseg * 8] =
                *(const uint4*)&KT[(size_t)(j0 + krow) * 512 + hc + kseg * 8];
        }
        #pragma unroll
        for (int i = 0; i < 2; i++) {      // V: 512 uint4 (32 rows x 16 segs)
            int idx = t + (i << 8);
            int vrow = idx >> 4, vseg = idx & 15;
            *(uint4*)&Vt[vrow][vseg * 8] =
                *(const uint4*)&Vh[(size_t)vrow * NTOK + j0 + vseg * 8];
        }
        __syncthreads();

        #pragma unroll
        for (int h2 = 0; h2 < 2; h2++) {   // two 64-key sub-passes
            f32x4 st[4][2];
            #pragma unroll
            for (int kt = 0; kt < 4; kt++) {
                bf16x8 kf = ldfrag(&Kt[h2 * 64 + kt * 16 + q15][quad * 8]);
                #pragma unroll
                for (int qi = 0; qi < 2; qi++) {
                    f32x4 z = {0.f, 0.f, 0.f, 0.f};
                    st[kt][qi] = __builtin_amdgcn_mfma_f32_16x16x32_bf16(kf, qf[qi], z, 0, 0, 0);
                }
            }

            #pragma unroll
            for (int kt = 0; kt < 4; kt++)
                #pragma unroll
                for (int r = 0; r < 4; r++) {
                    st[kt][0][r] = __expf(st[kt][0][r]);
                    st[kt][1][r] = __expf(st[kt][1][r]);
                }

            asm volatile("" ::: "memory");
            #pragma unroll
            for (int kt = 0; kt < 4; kt++)
                #pragma unroll
                for (int qi = 0; qi < 2; qi++) {
                    uint2 pp;
                    pp.x = packh2(st[kt][qi][0], st[kt][qi][1]);
                    pp.y = packh2(st[kt][qi][2], st[kt][qi][3]);
                    *(uint2*)&Plu[w][qi * 16 + q15][kt * 8 + quad * 2] = pp;
                }
            asm volatile("" ::: "memory");

            #pragma unroll
            for (int kc = 0; kc < 2; kc++) {
                f16x8 v0 = ldfragh(&Vt[q15][h2 * 64 + kc * 32 + quad * 8]);
                f16x8 v1 = ldfragh(&Vt[16 + q15][h2 * 64 + kc * 32 + quad * 8]);
                #pragma unroll
                for (int qi = 0; qi < 2; qi++) {
                    uint4 pu = *(const uint4*)&Plu[w][qi * 16 + q15][kc * 16 + quad * 4];
                    f16x8 pf = __builtin_bit_cast(f16x8, pu);
                    o[qi][0] = __builtin_amdgcn_mfma_f32_16x16x32_f16(pf, v0, o[qi][0], 0, 0, 0);
                    o[qi][1] = __builtin_amdgcn_mfma_f32_16x16x32_f16(pf, v1, o[qi][1], 0, 0, 0);
                    lacc[qi] = __builtin_amdgcn_mfma_f32_16x16x32_f16(pf, ones, lacc[qi], 0, 0, 0);
                }
            }
        }
    }

    #pragma unroll
    for (int qi = 0; qi < 2; qi++)
        #pragma unroll
        for (int r = 0; r < 4; r++) {
            float li = 1.f / lacc[qi][r];
            int q = quad * 4 + r;
            QT[(size_t)(qbase + qi * 16 + q) * 512 + hc + q15]      = f2b(o[qi][0][r] * li);
            QT[(size_t)(qbase + qi * 16 + q) * 512 + hc + 16 + q15] = f2b(o[qi][1][r] * li);
        }
}

// ---- Output projection: tile 64m x 64n, grid (64, 8). A = Wb[3] copy-staged.
__global__ __launch_bounds__(256) void oproj_mfma(const ushort_t* __restrict__ OT,
                                                  const ushort_t* __restrict__ Wob,
                                                  const float* __restrict__ bo,
                                                  const float* __restrict__ x,
                                                  float* __restrict__ out) {
    __shared__ __align__(16) ushort_t Wl[64][40];
    __shared__ __align__(16) ushort_t Bn[64][40];
    int t = threadIdx.x;
    int nbase = blockIdx.x << 6;
    int obase = blockIdx.y << 6;
    int w = t >> 6, lane = t & 63, q15 = lane & 15, quad = lane >> 4;

    f32x4 acc[4];
    #pragma unroll
    for (int i = 0; i < 4; i++) acc[i] = (f32x4){0.f, 0.f, 0.f, 0.f};

    int arow = t >> 2, aseg = t & 3;
    for (int ck = 0; ck < 512; ck += 32) {
        __syncthreads();
        *(uint4*)&Wl[arow][aseg * 8] =
            *(const uint4*)&Wob[(size_t)(obase + arow) * 512 + ck + aseg * 8];
        *(uint4*)&Bn[arow][aseg * 8] =
            *(const uint4*)&OT[(size_t)(nbase + arow) * 512 + ck + aseg * 8];
        __syncthreads();
        bf16x8 af = ldfrag(&Wl[w * 16 + q15][quad * 8]);
        #pragma unroll
        for (int n8 = 0; n8 < 4; n8++) {
            bf16x8 bfv = ldfrag(&Bn[n8 * 16 + q15][quad * 8]);
            acc[n8] = __builtin_amdgcn_mfma_f32_16x16x32_bf16(af, bfv, acc[n8], 0, 0, 0);
        }
    }

    #pragma unroll
    for (int r = 0; r < 4; r++) {
        int o = obase + w * 16 + quad * 4 + r;
        float b = bo[o];
        #pragma unroll
        for (int n8 = 0; n8 < 4; n8++) {
            size_t idx = (size_t)o * NTOK + nbase + n8 * 16 + q15;
            out[idx] = (acc[n8][r] + b + x[idx]) * RSQRT2;
        }
    }
}

extern "C" void kernel_launch(void* const* d_in, const int* in_sizes, int n_in,
                              void* d_out, int out_size, void* d_ws, size_t ws_size,
                              hipStream_t stream) {
    const float* x   = (const float*)d_in[0];
    const float* gnw = (const float*)d_in[1];
    const float* gnb = (const float*)d_in[2];
    const float* wq  = (const float*)d_in[3];
    const float* bq  = (const float*)d_in[4];
    const float* wk  = (const float*)d_in[5];
    const float* bk  = (const float*)d_in[6];
    const float* wv  = (const float*)d_in[7];
    const float* bv  = (const float*)d_in[8];
    const float* wo  = (const float*)d_in[9];
    const float* bo  = (const float*)d_in[10];
    float* out = (float*)d_out;

    if (ws_size < WS_NEEDED) {
        diag_kernel<<<1, 64, 0, stream>>>(out, (float)(ws_size >> 16));
        return;
    }

    char* wsb = (char*)d_ws;
    float* S   = (float*)(wsb + 0);
    float* SS  = (float*)(wsb + 2048);
    float* qa  = (float*)(wsb + 4096);
    float* qd  = (float*)(wsb + 6144);
    float* va  = (float*)(wsb + 8192);
    float* vd  = (float*)(wsb + 10240);
    float* bqf = (float*)(wsb + 12288);
    float* bkf = (float*)(wsb + 14336);
    float* bvf = (float*)(wsb + 16384);
    ushort_t* Wb = (ushort_t*)(wsb + WB_OFF);    // 2 MB bf16 (wq'|wk'|wv'|wo)
    ushort_t* QT = (ushort_t*)(wsb + QT_OFF);    // 4 MB bf16 [4096][512] (becomes O)
    ushort_t* KT = (ushort_t*)d_out;                        // 4 MB bf16 [4096][512]
    ushort_t* Vb = (ushort_t*)d_out + (size_t)CHAN * NTOK;  // 4 MB f16 [512][4096]

    gn_sums<<<512, 256, 0, stream>>>(x, S, SS);
    gn_coef<<<1, 512, 0, stream>>>(S, SS, gnw, gnb, qa, qd, va, vd);
    bias_fold<<<384, 256, 0, stream>>>(wq, wk, wv, bq, bk, bv, qd, vd, bqf, bkf, bvf);
    wprep<<<dim3(256, 4), 256, 0, stream>>>(wq, wk, wv, wo, qa, va, Wb);

    qkv_mfma<<<dim3(64, 12), 256, 0, stream>>>(x, Wb, bqf, bkf, bvf, QT, KT, Vb);

    attn_v7<<<dim3(32, 16), 256, 0, stream>>>(QT, KT, Vb);

    oproj_mfma<<<dim3(64, 8), 256, 0, stream>>>(QT, Wb + (size_t)3 * 262144, bo, x, out);
}

// Round 19
// 185.131 us; speedup vs baseline: 1.0632x; 1.0632x over previous
//
#include <hip/hip_runtime.h>

#define NTOK 4096
#define CHAN 512
#define GSIZE 65536
#define RSQRT2 0.7071067811865476f
#define SCALE 0.17677669529663687f   // 1/sqrt(32)
#define WB_OFF 32768
#define QT_OFF (WB_OFF + 2097152)
#define WS_NEEDED ((size_t)(QT_OFF + 4194304))

typedef unsigned short ushort_t;
typedef __attribute__((ext_vector_type(8))) short bf16x8;
typedef __attribute__((ext_vector_type(8))) _Float16 f16x8;
typedef __attribute__((ext_vector_type(4))) float f32x4;

__device__ __forceinline__ ushort_t f2b(float f) {
    unsigned u = __float_as_uint(f);
    unsigned r = (u + 0x7FFFu + ((u >> 16) & 1u)) >> 16;
    return (ushort_t)r;
}
__device__ __forceinline__ unsigned pack2r(float a, float b) {
    unsigned ua = __float_as_uint(a), ub = __float_as_uint(b);
    return ((ua + 0x8000u) >> 16) | ((ub + 0x8000u) & 0xFFFF0000u);
}
__device__ __forceinline__ unsigned packh2(float a, float b) {
    return __builtin_bit_cast(unsigned, __builtin_amdgcn_cvt_pkrtz(a, b));
}
__device__ __forceinline__ ushort_t f2h(float f) {
    return (ushort_t)(packh2(f, f) & 0xFFFFu);
}
__device__ __forceinline__ bf16x8 ldfrag(const ushort_t* p) {
    return __builtin_bit_cast(bf16x8, *(const uint4*)p);
}
__device__ __forceinline__ f16x8 ldfragh(const ushort_t* p) {
    return __builtin_bit_cast(f16x8, *(const uint4*)p);
}

__global__ void diag_kernel(float* out, float v) {
    if (threadIdx.x == 0 && blockIdx.x == 0) out[0] = v;
}

// ---- GN pass A: per-channel sums. One block per channel (512 blocks).
__global__ __launch_bounds__(256) void gn_sums(const float* __restrict__ x,
                                               float* __restrict__ S,
                                               float* __restrict__ SS) {
    int c = blockIdx.x, t = threadIdx.x;
    const float4* p = (const float4*)(x + (size_t)c * 4096);
    float s = 0.f, ss = 0.f;
    #pragma unroll
    for (int i = 0; i < 4; i++) {
        float4 f = p[i * 256 + t];
        s += f.x + f.y + f.z + f.w;
        ss += f.x * f.x + f.y * f.y + f.z * f.z + f.w * f.w;
    }
    #pragma unroll
    for (int off = 32; off > 0; off >>= 1) {
        s += __shfl_xor(s, off);
        ss += __shfl_xor(ss, off);
    }
    __shared__ float as[4], bs[4];
    int w = t >> 6;
    if ((t & 63) == 0) { as[w] = s; bs[w] = ss; }
    __syncthreads();
    if (t == 0) {
        S[c] = as[0] + as[1] + as[2] + as[3];
        SS[c] = bs[0] + bs[1] + bs[2] + bs[3];
    }
}

// ---- GN pass B: coefficients. 1 block x 512 threads (thread = channel).
__global__ __launch_bounds__(512) void gn_coef(const float* __restrict__ S,
                                               const float* __restrict__ SS,
                                               const float* __restrict__ gnw,
                                               const float* __restrict__ gnb,
                                               float* __restrict__ qa,
                                               float* __restrict__ qd,
                                               float* __restrict__ va,
                                               float* __restrict__ vd) {
    int c = threadIdx.x;
    float Sc = S[c], SSc = SS[c];
    float gs = Sc, gss = SSc;
    #pragma unroll
    for (int off = 1; off < 16; off <<= 1) {
        gs += __shfl_xor(gs, off);
        gss += __shfl_xor(gss, off);
    }
    float mu = gs * (1.f / GSIZE);
    float var = gss * (1.f / GSIZE) - mu * mu;
    float r1 = rsqrtf(var + 1e-6f);
    float wc = gnw[c], bc = gnb[c];
    float a1 = r1 * wc;
    float d1 = bc - mu * a1;
    qa[c] = a1; qd[c] = d1;
    float S2 = a1 * Sc + 4096.f * d1;
    float SS2 = a1 * a1 * SSc + 2.f * a1 * d1 * Sc + 4096.f * d1 * d1;
    float gs2 = S2, gss2 = SS2;
    #pragma unroll
    for (int off = 1; off < 16; off <<= 1) {
        gs2 += __shfl_xor(gs2, off);
        gss2 += __shfl_xor(gss2, off);
    }
    float mu2 = gs2 * (1.f / GSIZE);
    float var2 = gss2 * (1.f / GSIZE) - mu2 * mu2;
    float r2 = rsqrtf(var2 + 1e-6f);
    float a2 = r2 * wc;
    va[c] = a1 * a2;
    vd[c] = a2 * (d1 - mu2) + bc;
}

// ---- Fold GN offsets into biases: b'[o] = b[o] + sum_c W[o][c]*d[c].
__global__ __launch_bounds__(256) void bias_fold(const float* __restrict__ wq,
                                                 const float* __restrict__ wk,
                                                 const float* __restrict__ wv,
                                                 const float* __restrict__ bq,
                                                 const float* __restrict__ bk,
                                                 const float* __restrict__ bv,
                                                 const float* __restrict__ qd,
                                                 const float* __restrict__ vd,
                                                 float* __restrict__ bqf,
                                                 float* __restrict__ bkf,
                                                 float* __restrict__ bvf) {
    int row = blockIdx.x * 4 + (threadIdx.x >> 6);   // 0..1535
    int lane = threadIdx.x & 63;
    int m = row >> 9;
    int o = row & 511;
    const float* W = (m == 0) ? wq : (m == 1) ? wk : wv;
    const float* b = (m == 0) ? bq : (m == 1) ? bk : bv;
    const float* d = (m == 0) ? qd : vd;
    float* outp    = (m == 0) ? bqf : (m == 1) ? bkf : bvf;
    const float4* wr = (const float4*)(W + (size_t)o * 512) + lane * 2;
    const float4* dr = (const float4*)d + lane * 2;
    float4 a0 = wr[0], a1 = wr[1], d0 = dr[0], d1 = dr[1];
    float acc = a0.x * d0.x + a0.y * d0.y + a0.z * d0.z + a0.w * d0.w
              + a1.x * d1.x + a1.y * d1.y + a1.z * d1.z + a1.w * d1.w;
    #pragma unroll
    for (int off = 32; off > 0; off >>= 1) acc += __shfl_xor(acc, off);
    if (lane == 0) outp[o] = b[o] + acc;
}

// ---- Weight prep: fp32 -> bf16 once, GN affine folded into wq/wk/wv.
__global__ __launch_bounds__(256) void wprep(const float* __restrict__ wq,
                                             const float* __restrict__ wk,
                                             const float* __restrict__ wv,
                                             const float* __restrict__ wo,
                                             const float* __restrict__ qa,
                                             const float* __restrict__ va,
                                             ushort_t* __restrict__ Wb) {
    int y = blockIdx.y;
    const float* src = (y == 0) ? wq : (y == 1) ? wk : (y == 2) ? wv : wo;
    int i = (blockIdx.x * 256 + threadIdx.x) * 4;
    float4 f = *(const float4*)(src + i);
    if (y < 3) {
        const float* aff = (y == 0) ? qa : va;
        float4 a = *(const float4*)(aff + (i & 511));
        f.x *= a.x; f.y *= a.y; f.z *= a.z; f.w *= a.w;
    }
    uint2 u;
    u.x = pack2r(f.x, f.y);
    u.y = pack2r(f.z, f.w);
    *(uint2*)(Wb + (size_t)y * 262144 + i) = u;
}

// ---- QKV projection. Tile 128m x 64n, K-step 64, grid (64, 12).
// A = Wb uint4 copy; B = x fp32, tok-per-lane staging (coalesced global,
// row-contiguous conflict-light b128 LDS writes — fixes round-18's 8-way).
__global__ __launch_bounds__(256) void qkv_mfma(const float* __restrict__ x,
                                                const ushort_t* __restrict__ Wb,
                                                const float* __restrict__ bqf,
                                                const float* __restrict__ bkf,
                                                const float* __restrict__ bvf,
                                                ushort_t* __restrict__ QT,
                                                ushort_t* __restrict__ KT,
                                                ushort_t* __restrict__ Vb) {
    __shared__ __align__(16) ushort_t Wl[128][72];
    __shared__ __align__(16) ushort_t Bn[64][72];
    __shared__ __align__(16) ushort_t Tl[64][136];
    int t = threadIdx.x;
    int nbase = blockIdx.x << 6;
    int y = blockIdx.y;
    int buf = y >> 2;
    int obase = (y & 3) << 7;
    const ushort_t* Wsrc = Wb + (size_t)buf * 262144;
    const float* bias = (buf == 0) ? bqf : (buf == 1) ? bkf : bvf;

    int w = t >> 6, lane = t & 63, q15 = lane & 15, quad = lane >> 4;
    f32x4 acc[2][4];
    #pragma unroll
    for (int i = 0; i < 2; i++)
        #pragma unroll
        for (int j = 0; j < 4; j++) acc[i][j] = (f32x4){0.f, 0.f, 0.f, 0.f};

    int tok = t & 63, c8 = t >> 6;         // B staging roles
    for (int ck = 0; ck < 512; ck += 64) {
        __syncthreads();
        #pragma unroll
        for (int i = 0; i < 4; i++) {      // A: 1024 uint4 = 128 rows x 64 k
            int idx = 4 * t + i;
            int row = idx >> 3, seg = idx & 7;
            *(uint4*)&Wl[row][seg * 8] =
                *(const uint4*)&Wsrc[(size_t)(obase + row) * 512 + ck + seg * 8];
        }
        {   // B: 64 tok x 64 chans; lane = tok (coalesced), 16 chans each
            float v[16];
            #pragma unroll
            for (int i = 0; i < 16; i++)
                v[i] = x[(size_t)(ck + c8 * 16 + i) * NTOK + nbase + tok];
            uint4 u0, u1;
            u0.x = pack2r(v[0], v[1]);   u0.y = pack2r(v[2], v[3]);
            u0.z = pack2r(v[4], v[5]);   u0.w = pack2r(v[6], v[7]);
            u1.x = pack2r(v[8], v[9]);   u1.y = pack2r(v[10], v[11]);
            u1.z = pack2r(v[12], v[13]); u1.w = pack2r(v[14], v[15]);
            *(uint4*)&Bn[tok][c8 * 16] = u0;
            *(uint4*)&Bn[tok][c8 * 16 + 8] = u1;
        }
        __syncthreads();
        #pragma unroll
        for (int kk = 0; kk < 2; kk++) {
            bf16x8 af0 = ldfrag(&Wl[w * 32 + q15][kk * 32 + quad * 8]);
            bf16x8 af1 = ldfrag(&Wl[w * 32 + 16 + q15][kk * 32 + quad * 8]);
            #pragma unroll
            for (int n8 = 0; n8 < 4; n8++) {
                bf16x8 bfv = ldfrag(&Bn[n8 * 16 + q15][kk * 32 + quad * 8]);
                acc[0][n8] = __builtin_amdgcn_mfma_f32_16x16x32_bf16(af0, bfv, acc[0][n8], 0, 0, 0);
                acc[1][n8] = __builtin_amdgcn_mfma_f32_16x16x32_bf16(af1, bfv, acc[1][n8], 0, 0, 0);
            }
        }
    }

    if (buf == 2) {   // V: f16 [chan][tok]
        #pragma unroll
        for (int mi = 0; mi < 2; mi++)
            #pragma unroll
            for (int r = 0; r < 4; r++) {
                int o = obase + w * 32 + mi * 16 + quad * 4 + r;
                float bo = bias[o];
                #pragma unroll
                for (int n8 = 0; n8 < 4; n8++)
                    Vb[(size_t)o * NTOK + nbase + n8 * 16 + q15] = f2h(acc[mi][n8][r] + bo);
            }
        return;
    }

    // Q/K: transpose via Tl, full 1024-uint4 flush
    ushort_t* dstT = (buf == 0) ? QT : KT;
    float qs = (buf == 0) ? SCALE : 1.0f;
    __syncthreads();
    #pragma unroll
    for (int mi = 0; mi < 2; mi++)
        #pragma unroll
        for (int r = 0; r < 4; r++) {
            int mloc = w * 32 + mi * 16 + quad * 4 + r;
            float bo = bias[obase + mloc];
            #pragma unroll
            for (int n8 = 0; n8 < 4; n8++)
                Tl[n8 * 16 + q15][mloc] = f2b((acc[mi][n8][r] + bo) * qs);
        }
    __syncthreads();
    #pragma unroll
    for (int i = 0; i < 4; i++) {
        int idx = 4 * t + i;                // 1024 uint4: 64 rows x 16 segs
        int row = idx >> 4, ch = idx & 15;
        uint4 u = *(const uint4*)&Tl[row][ch * 8];
        *(uint4*)&dstT[(size_t)(nbase + row) * 512 + obase + ch * 8] = u;
    }
}

// ---- Attention v8: 128 q/block (4 waves x 32 q, 2 Q-frags), K-tile 256
// (4 x 64-key sub-passes — halves barrier drains vs v7 at same 2 blocks/CU),
// Plu stride 44 (conflict-free writes). QK bf16, __expf, P/V f16, l via MFMA.
__global__ __launch_bounds__(256) void attn_v8(ushort_t* __restrict__ QT,
                                               const ushort_t* __restrict__ KT,
                                               const ushort_t* __restrict__ V) {
    __shared__ __align__(16) ushort_t Kt[256][40];    // [key][32 chans] bf16
    __shared__ __align__(16) ushort_t Vt[32][264];    // [d][256 keys] f16
    __shared__ __align__(16) unsigned Plu[4][32][44]; // per-wave [q][key-pairs] f16
    int h = blockIdx.y;
    int t = threadIdx.x;
    int w = t >> 6, lane = t & 63, q15 = lane & 15, quad = lane >> 4;
    int qbase = (blockIdx.x << 7) + w * 32;           // wave-private 32 queries
    int hc = h * 32;
    const ushort_t* Vh = V + (size_t)hc * NTOK;

    bf16x8 qf[2];
    #pragma unroll
    for (int qi = 0; qi < 2; qi++)
        qf[qi] = ldfrag(&QT[(size_t)(qbase + qi * 16 + q15) * 512 + hc + quad * 8]);

    const uint4 onesu = {0x3C003C00u, 0x3C003C00u, 0x3C003C00u, 0x3C003C00u};
    const f16x8 ones = __builtin_bit_cast(f16x8, onesu);

    f32x4 o[2][2];
    #pragma unroll
    for (int qi = 0; qi < 2; qi++)
        #pragma unroll
        for (int dc = 0; dc < 2; dc++) o[qi][dc] = (f32x4){0.f, 0.f, 0.f, 0.f};
    f32x4 lacc[2] = {{0.f, 0.f, 0.f, 0.f}, {0.f, 0.f, 0.f, 0.f}};

    for (int j0 = 0; j0 < NTOK; j0 += 256) {
        __syncthreads();
        #pragma unroll
        for (int i = 0; i < 4; i++) {      // K: 1024 uint4 (256 rows x 4 segs)
            int idx = t + (i << 8);
            int krow = idx >> 2, kseg = idx & 3;
            *(uint4*)&Kt[krow][kseg * 8] =
                *(const uint4*)&KT[(size_t)(j0 + krow) * 512 + hc + kseg * 8];
        }
        #pragma unroll
        for (int i = 0; i < 4; i++) {      // V: 1024 uint4 (32 rows x 32 segs)
            int idx = t + (i << 8);
            int vrow = idx >> 5, vseg = idx & 31;
            *(uint4*)&Vt[vrow][vseg * 8] =
                *(const uint4*)&Vh[(size_t)vrow * NTOK + j0 + vseg * 8];
        }
        __syncthreads();

        #pragma unroll
        for (int h2 = 0; h2 < 4; h2++) {   // four 64-key sub-passes
            f32x4 st[4][2];
            #pragma unroll
            for (int kt = 0; kt < 4; kt++) {
                bf16x8 kf = ldfrag(&Kt[h2 * 64 + kt * 16 + q15][quad * 8]);
                #pragma unroll
                for (int qi = 0; qi < 2; qi++) {
                    f32x4 z = {0.f, 0.f, 0.f, 0.f};
                    st[kt][qi] = __builtin_amdgcn_mfma_f32_16x16x32_bf16(kf, qf[qi], z, 0, 0, 0);
                }
            }

            #pragma unroll
            for (int kt = 0; kt < 4; kt++)
                #pragma unroll
                for (int r = 0; r < 4; r++) {
                    st[kt][0][r] = __expf(st[kt][0][r]);
                    st[kt][1][r] = __expf(st[kt][1][r]);
                }

            asm volatile("" ::: "memory");
            #pragma unroll
            for (int kt = 0; kt < 4; kt++)
                #pragma unroll
                for (int qi = 0; qi < 2; qi++) {
                    uint2 pp;
                    pp.x = packh2(st[kt][qi][0], st[kt][qi][1]);
                    pp.y = packh2(st[kt][qi][2], st[kt][qi][3]);
                    *(uint2*)&Plu[w][qi * 16 + q15][kt * 8 + quad * 2] = pp;
                }
            asm volatile("" ::: "memory");

            #pragma unroll
            for (int kc = 0; kc < 2; kc++) {
                f16x8 v0 = ldfragh(&Vt[q15][h2 * 64 + kc * 32 + quad * 8]);
                f16x8 v1 = ldfragh(&Vt[16 + q15][h2 * 64 + kc * 32 + quad * 8]);
                #pragma unroll
                for (int qi = 0; qi < 2; qi++) {
                    uint4 pu = *(const uint4*)&Plu[w][qi * 16 + q15][kc * 16 + quad * 4];
                    f16x8 pf = __builtin_bit_cast(f16x8, pu);
                    o[qi][0] = __builtin_amdgcn_mfma_f32_16x16x32_f16(pf, v0, o[qi][0], 0, 0, 0);
                    o[qi][1] = __builtin_amdgcn_mfma_f32_16x16x32_f16(pf, v1, o[qi][1], 0, 0, 0);
                    lacc[qi] = __builtin_amdgcn_mfma_f32_16x16x32_f16(pf, ones, lacc[qi], 0, 0, 0);
                }
            }
        }
    }

    #pragma unroll
    for (int qi = 0; qi < 2; qi++)
        #pragma unroll
        for (int r = 0; r < 4; r++) {
            float li = 1.f / lacc[qi][r];
            int q = quad * 4 + r;
            QT[(size_t)(qbase + qi * 16 + q) * 512 + hc + q15]      = f2b(o[qi][0][r] * li);
            QT[(size_t)(qbase + qi * 16 + q) * 512 + hc + 16 + q15] = f2b(o[qi][1][r] * li);
        }
}

// ---- Output projection: tile 64m x 64n, grid (64, 8). A = Wb[3] copy-staged.
__global__ __launch_bounds__(256) void oproj_mfma(const ushort_t* __restrict__ OT,
                                                  const ushort_t* __restrict__ Wob,
                                                  const float* __restrict__ bo,
                                                  const float* __restrict__ x,
                                                  float* __restrict__ out) {
    __shared__ __align__(16) ushort_t Wl[64][40];
    __shared__ __align__(16) ushort_t Bn[64][40];
    int t = threadIdx.x;
    int nbase = blockIdx.x << 6;
    int obase = blockIdx.y << 6;
    int w = t >> 6, lane = t & 63, q15 = lane & 15, quad = lane >> 4;

    f32x4 acc[4];
    #pragma unroll
    for (int i = 0; i < 4; i++) acc[i] = (f32x4){0.f, 0.f, 0.f, 0.f};

    int arow = t >> 2, aseg = t & 3;
    for (int ck = 0; ck < 512; ck += 32) {
        __syncthreads();
        *(uint4*)&Wl[arow][aseg * 8] =
            *(const uint4*)&Wob[(size_t)(obase + arow) * 512 + ck + aseg * 8];
        *(uint4*)&Bn[arow][aseg * 8] =
            *(const uint4*)&OT[(size_t)(nbase + arow) * 512 + ck + aseg * 8];
        __syncthreads();
        bf16x8 af = ldfrag(&Wl[w * 16 + q15][quad * 8]);
        #pragma unroll
        for (int n8 = 0; n8 < 4; n8++) {
            bf16x8 bfv = ldfrag(&Bn[n8 * 16 + q15][quad * 8]);
            acc[n8] = __builtin_amdgcn_mfma_f32_16x16x32_bf16(af, bfv, acc[n8], 0, 0, 0);
        }
    }

    #pragma unroll
    for (int r = 0; r < 4; r++) {
        int o = obase + w * 16 + quad * 4 + r;
        float b = bo[o];
        #pragma unroll
        for (int n8 = 0; n8 < 4; n8++) {
            size_t idx = (size_t)o * NTOK + nbase + n8 * 16 + q15;
            out[idx] = (acc[n8][r] + b + x[idx]) * RSQRT2;
        }
    }
}

extern "C" void kernel_launch(void* const* d_in, const int* in_sizes, int n_in,
                              void* d_out, int out_size, void* d_ws, size_t ws_size,
                              hipStream_t stream) {
    const float* x   = (const float*)d_in[0];
    const float* gnw = (const float*)d_in[1];
    const float* gnb = (const float*)d_in[2];
    const float* wq  = (const float*)d_in[3];
    const float* bq  = (const float*)d_in[4];
    const float* wk  = (const float*)d_in[5];
    const float* bk  = (const float*)d_in[6];
    const float* wv  = (const float*)d_in[7];
    const float* bv  = (const float*)d_in[8];
    const float* wo  = (const float*)d_in[9];
    const float* bo  = (const float*)d_in[10];
    float* out = (float*)d_out;

    if (ws_size < WS_NEEDED) {
        diag_kernel<<<1, 64, 0, stream>>>(out, (float)(ws_size >> 16));
        return;
    }

    char* wsb = (char*)d_ws;
    float* S   = (float*)(wsb + 0);
    float* SS  = (float*)(wsb + 2048);
    float* qa  = (float*)(wsb + 4096);
    float* qd  = (float*)(wsb + 6144);
    float* va  = (float*)(wsb + 8192);
    float* vd  = (float*)(wsb + 10240);
    float* bqf = (float*)(wsb + 12288);
    float* bkf = (float*)(wsb + 14336);
    float* bvf = (float*)(wsb + 16384);
    ushort_t* Wb = (ushort_t*)(wsb + WB_OFF);    // 2 MB bf16 (wq'|wk'|wv'|wo)
    ushort_t* QT = (ushort_t*)(wsb + QT_OFF);    // 4 MB bf16 [4096][512] (becomes O)
    ushort_t* KT = (ushort_t*)d_out;                        // 4 MB bf16 [4096][512]
    ushort_t* Vb = (ushort_t*)d_out + (size_t)CHAN * NTOK;  // 4 MB f16 [512][4096]

    gn_sums<<<512, 256, 0, stream>>>(x, S, SS);
    gn_coef<<<1, 512, 0, stream>>>(S, SS, gnw, gnb, qa, qd, va, vd);
    bias_fold<<<384, 256, 0, stream>>>(wq, wk, wv, bq, bk, bv, qd, vd, bqf, bkf, bvf);
    wprep<<<dim3(256, 4), 256, 0, stream>>>(wq, wk, wv, wo, qa, va, Wb);

    qkv_mfma<<<dim3(64, 12), 256, 0, stream>>>(x, Wb, bqf, bkf, bvf, QT, KT, Vb);

    attn_v8<<<dim3(32, 16), 256, 0, stream>>>(QT, KT, Vb);

    oproj_mfma<<<dim3(64, 8), 256, 0, stream>>>(QT, Wb + (size_t)3 * 262144, bo, x, out);
}